// Round 7
// baseline (35160.123 us; speedup 1.0000x reference)
//
#include <hip/hip_runtime.h>
#include <math.h>

#define Vc 50257
#define NEG_INF (-__builtin_inff())
#define VCOLS 512
#define NVB 99      // 99*512 = 50688 >= 50257
#define NB  8

// ---- workspace float offsets (no flags, no atomics; coherence = kernel boundaries) ----
#define WS_PE    0        // [63][64] pe rows (rows 1..62 used)
#define WS_WV    4096     // [8][64]
#define WS_CS    4608     // [2 layers][2][64] column sums of ca_W k/v proj
#define WS_TOKF  4864     // [8][64]
#define WS_MS    5376     // [8][2] global m,S of previous step
#define WS_SM    8192     // stats_m [8][128] (use NVB)
#define WS_SS    9216     // stats_s [8][128]
#define WS_SI    10240    // stats_i [8][128] (int)
#define WS_X1    16384    // [8][64][64] row inputs y
#define WS_Q1    (WS_X1 + 32768)
#define WS_K1    (WS_Q1 + 32768)
#define WS_V1    (WS_K1 + 32768)   // end 147456 floats = 590 KB

// ---------------- wave-level helpers ----------------

__device__ __forceinline__ float wsum64(float v) {
#pragma unroll
  for (int m = 32; m >= 1; m >>= 1) v += __shfl_xor(v, m, 64);
  return v;
}

__device__ __forceinline__ float red8(float v) {
  v += __shfl_xor(v, 1, 64);
  v += __shfl_xor(v, 2, 64);
  v += __shfl_xor(v, 4, 64);
  return v;
}

// out[lane] = bias[lane] + sum_e x[e]*W[e*64+lane]; x broadcast via LDS float4 reads
__device__ __forceinline__ float proj_lds(float xv, float* xb,
                                          const float* __restrict__ W,
                                          const float* __restrict__ bias, int lane) {
  xb[lane] = xv;
  asm volatile("s_waitcnt lgkmcnt(0)" ::: "memory");
  float acc = bias[lane];
  const float4* x4 = (const float4*)xb;
#pragma unroll
  for (int i = 0; i < 16; ++i) {
    float4 xc = x4[i];
    acc = fmaf(xc.x, W[(4 * i + 0) * 64 + lane], acc);
    acc = fmaf(xc.y, W[(4 * i + 1) * 64 + lane], acc);
    acc = fmaf(xc.z, W[(4 * i + 2) * 64 + lane], acc);
    acc = fmaf(xc.w, W[(4 * i + 3) * 64 + lane], acc);
  }
  asm volatile("" ::: "memory");
  return acc;
}

__device__ __forceinline__ float ln64(float xv, const float* __restrict__ g,
                                      const float* __restrict__ b, int lane) {
  float mean = wsum64(xv) * 0.015625f;
  float d = xv - mean;
  float var = wsum64(d * d) * 0.015625f;
  float r = 1.0f / sqrtf(var + 1e-5f);
  return d * r * g[lane] + b[lane];
}

struct LayerR {
  const float *saW3, *sab3, *caW0, *cab0, *caW3, *cab3,
              *ffW1, *ffb1, *ffW2, *ffb2, *g0, *be0, *g1, *be1, *g2, *be2;
  float cs1_r, cs2_r, cab1_r, cab2_r;
};

__device__ __forceinline__ void build_layer(LayerR& L, int n, int lane,
    const float* sa_W, const float* sa_b, const float* ca_W, const float* ca_b,
    const float* ff_W1, const float* ff_b1, const float* ff_W2, const float* ff_b2,
    const float* ln_g, const float* ln_b, const float* cs_g) {
  L.saW3 = sa_W + (n * 4 + 3) * 4096; L.sab3 = sa_b + (n * 4 + 3) * 64;
  L.caW0 = ca_W + (n * 4 + 0) * 4096; L.cab0 = ca_b + (n * 4 + 0) * 64;
  L.caW3 = ca_W + (n * 4 + 3) * 4096; L.cab3 = ca_b + (n * 4 + 3) * 64;
  L.ffW1 = ff_W1 + n * 4096;          L.ffb1 = ff_b1 + n * 64;
  L.ffW2 = ff_W2 + n * 4096;          L.ffb2 = ff_b2 + n * 64;
  L.g0 = ln_g + (n * 3 + 0) * 64;     L.be0 = ln_b + (n * 3 + 0) * 64;
  L.g1 = ln_g + (n * 3 + 1) * 64;     L.be1 = ln_b + (n * 3 + 1) * 64;
  L.g2 = ln_g + (n * 3 + 2) * 64;     L.be2 = ln_b + (n * 3 + 2) * 64;
  L.cab1_r = ca_b[(n * 4 + 1) * 64 + lane];
  L.cab2_r = ca_b[(n * 4 + 2) * 64 + lane];
  L.cs1_r = cs_g[(n * 2 + 0) * 64 + lane];
  L.cs2_r = cs_g[(n * 2 + 1) * 64 + lane];
}

// One wave, one row. K/V in LDS with row stride 65 (bank = (k+e)%32 -> 2-way, free).
__device__ float transformer_row(int lane, int t, float x, float q,
                                 const float* Kb, const float* Vb,
                                 const float* wv, float* xb, float* pb,
                                 const LayerR& P) {
  const float ISQ8 = 0.35355339059327373f;  // 1/sqrt(8)
  // ---- scores: lane = k ----
  xb[lane] = q;
  asm volatile("s_waitcnt lgkmcnt(0)" ::: "memory");
  float a[8] = {0.f, 0.f, 0.f, 0.f, 0.f, 0.f, 0.f, 0.f};
  const float* Krow = Kb + lane * 65;
  const float4* xq4 = (const float4*)xb;
#pragma unroll
  for (int i = 0; i < 16; ++i) {
    float4 xc = xq4[i];
    a[i >> 1] = fmaf(xc.x, Krow[4 * i + 0], a[i >> 1]);
    a[i >> 1] = fmaf(xc.y, Krow[4 * i + 1], a[i >> 1]);
    a[i >> 1] = fmaf(xc.z, Krow[4 * i + 2], a[i >> 1]);
    a[i >> 1] = fmaf(xc.w, Krow[4 * i + 3], a[i >> 1]);
  }
  const bool act = lane < t;
  float m[8];
#pragma unroll
  for (int h = 0; h < 8; ++h) { a[h] = act ? a[h] * ISQ8 : NEG_INF; m[h] = a[h]; }
#pragma unroll
  for (int msk = 1; msk < 64; msk <<= 1) {
#pragma unroll
    for (int h = 0; h < 8; ++h) m[h] = fmaxf(m[h], __shfl_xor(m[h], msk, 64));
  }
  float l[8];
#pragma unroll
  for (int h = 0; h < 8; ++h) { a[h] = act ? expf(a[h] - m[h]) : 0.f; l[h] = a[h]; }
#pragma unroll
  for (int msk = 1; msk < 64; msk <<= 1) {
#pragma unroll
    for (int h = 0; h < 8; ++h) l[h] += __shfl_xor(l[h], msk, 64);
  }
#pragma unroll
  for (int h = 0; h < 8; ++h) pb[h * 64 + lane] = a[h] / l[h];
  asm volatile("s_waitcnt lgkmcnt(0)" ::: "memory");
  // ---- PV: lane = e ----
  const float* pr = pb + (lane >> 3) * 64;
  float attn = 0.f;
  for (int k = 0; k < t; ++k) attn = fmaf(pr[k], Vb[k * 65 + lane], attn);

  float y1 = ln64(x + proj_lds(attn, xb, P.saW3, P.sab3, lane), P.g0, P.be0, lane);
  float qc = proj_lds(y1, xb, P.caW0, P.cab0, lane);
  float pa = red8(qc * P.cs1_r);
  float pc = red8(qc * P.cab1_r);
  const float4* wv4 = (const float4*)wv;
  float mc = NEG_INF;
#pragma unroll
  for (int i = 0; i < 16; ++i) {
    float4 wq = wv4[i];
    int k = 4 * i;
    if (k + 0 < t) mc = fmaxf(mc, fmaf(pa, wq.x, pc));
    if (k + 1 < t) mc = fmaxf(mc, fmaf(pa, wq.y, pc));
    if (k + 2 < t) mc = fmaxf(mc, fmaf(pa, wq.z, pc));
    if (k + 3 < t) mc = fmaxf(mc, fmaf(pa, wq.w, pc));
  }
  float lc = 0.f, z = 0.f;
#pragma unroll
  for (int i = 0; i < 16; ++i) {
    float4 wq = wv4[i];
    int k = 4 * i;
    float wk[4] = {wq.x, wq.y, wq.z, wq.w};
#pragma unroll
    for (int j = 0; j < 4; ++j) {
      if (k + j < t) {
        float raw = fmaf(pa, wk[j], pc);
        float pw = expf((raw - mc) * ISQ8);
        lc += pw;
        z = fmaf(pw, wk[j], z);
      }
    }
  }
  float oc = fmaf(z / lc, P.cs2_r, P.cab2_r);
  float y2 = ln64(y1 + proj_lds(oc, xb, P.caW3, P.cab3, lane), P.g1, P.be1, lane);
  float f = fmaxf(proj_lds(y2, xb, P.ffW1, P.ffb1, lane), 0.f);
  float y3 = ln64(y2 + proj_lds(f, xb, P.ffW2, P.ffb2, lane), P.g2, P.be2, lane);
  return y3;
}

// =================== init: pe table, w-vector, ca column sums, seed row 0 ===================
__global__ __launch_bounds__(1024) void init_kernel(
    const float* __restrict__ noise, const float* __restrict__ lin_W,
    const float* __restrict__ lin_b, const float* __restrict__ sa_W,
    const float* __restrict__ sa_b, const float* __restrict__ ca_W,
    const float* __restrict__ emb, const int* __restrict__ start_id,
    float* __restrict__ wsf) {
  const int tid = threadIdx.x, lane = tid & 63, wvid = tid >> 6;
  __shared__ float xbuf[16 * 64];
  float* myxb = xbuf + wvid * 64;

  for (int i = tid; i < 62 * 64; i += 1024) {
    int t = 1 + (i >> 6), e = i & 63;
    double ang = (double)t / pow(10000.0, (double)(e & 62) / 64.0);
    wsf[WS_PE + t * 64 + e] = (e & 1) ? (float)cos(ang) : (float)sin(ang);
  }
  if (wvid < 8) {
    int b = wvid;
    float nz = noise[b * 64 + lane];
    float t1 = proj_lds(nz, myxb, lin_W, lin_b, lane);
    wsf[WS_WV + b * 64 + lane] = proj_lds(t1, myxb, lin_W + 4096, lin_b + 64, lane);
  } else if (wvid < 12) {
    int w = wvid - 8, n = w >> 1, which = w & 1;
    float c = 0.f;
    for (int e = 0; e < 64; ++e) c += ca_W[(n * 4 + 1 + which) * 4096 + e * 64 + lane];
    wsf[WS_CS + w * 64 + lane] = c;
  } else {
    for (int b = (wvid - 12) * 2; b <= (wvid - 12) * 2 + 1; ++b) {
      float y0 = emb[start_id[0] * 64 + lane] + ((lane & 1) ? 1.0f : 0.0f);
      float q0 = proj_lds(y0, myxb, sa_W, sa_b, lane);
      float k0 = proj_lds(y0, myxb, sa_W + 4096, sa_b + 64, lane);
      float v0 = proj_lds(y0, myxb, sa_W + 2 * 4096, sa_b + 128, lane);
      wsf[WS_X1 + b * 4096 + lane] = y0;
      wsf[WS_Q1 + b * 4096 + lane] = q0;
      wsf[WS_K1 + b * 4096 + lane] = k0;
      wsf[WS_V1 + b * 4096 + lane] = v0;
    }
  }
}

// =================== transformer step t: one block per batch ===================
// t in [1,64]. t>=2: reduce stats(t-1) -> mS,argmax; build row t-1.
// t<=63: stage K1/V1, layer-1 all rows < t (1 row/wave, 4 slots), layer-2 -> tokf.
__global__ __launch_bounds__(1024) void trans_kernel(
    const float* __restrict__ sa_W, const float* __restrict__ sa_b,
    const float* __restrict__ ca_W, const float* __restrict__ ca_b,
    const float* __restrict__ ff_W1, const float* __restrict__ ff_b1,
    const float* __restrict__ ff_W2, const float* __restrict__ ff_b2,
    const float* __restrict__ ln_g, const float* __restrict__ ln_b,
    const float* __restrict__ emb, float* __restrict__ wsf, int t) {
  const int tid = threadIdx.x, lane = tid & 63, wvid = tid >> 6;
  const int b = blockIdx.x;
  __shared__ float lds[26368];
  float* K1  = lds;            // 63 rows, stride 65
  float* V1  = lds + 4096;
  float* K2  = lds + 8192;
  float* V2  = lds + 12288;
  float* wvl = lds + 16384;
  float* x2s = lds + 16448;
  float* xbuf = lds + 16576;   // 16 waves * 64
  float* pbuf = lds + 17600;   // 16 waves * 512
  float* myxb = xbuf + wvid * 64;
  float* mypb = pbuf + wvid * 512;

  LayerR L0, L1;
  build_layer(L0, 0, lane, sa_W, sa_b, ca_W, ca_b, ff_W1, ff_b1, ff_W2, ff_b2,
              ln_g, ln_b, wsf + WS_CS);
  build_layer(L1, 1, lane, sa_W, sa_b, ca_W, ca_b, ff_W1, ff_b1, ff_W2, ff_b2,
              ln_g, ln_b, wsf + WS_CS);

  if (wvid == 0) wvl[lane] = wsf[WS_WV + b * 64 + lane];

  // ---- Phase A (wave 1): reduce vocab stats of step t-1; build row t-1 ----
  if (t >= 2 && wvid == 1) {
    const float* smp = wsf + WS_SM + b * 128;
    const float* ssp = wsf + WS_SS + b * 128;
    const int*   sip = (const int*)(wsf + WS_SI) + b * 128;
    float mA = smp[lane];
    float sA = ssp[lane];
    int   iA = sip[lane];
    const bool a2 = (64 + lane) < NVB;
    float mB = a2 ? smp[64 + lane] : NEG_INF;
    float sB = a2 ? ssp[64 + lane] : 0.f;
    int   iB = a2 ? sip[64 + lane] : 0x7fffffff;
    float mg = mA; int ig = iA;
    if (mB > mg || (mB == mg && iB < ig)) { mg = mB; ig = iB; }
#pragma unroll
    for (int msk = 1; msk < 64; msk <<= 1) {
      float om = __shfl_xor(mg, msk, 64);
      int oi = __shfl_xor(ig, msk, 64);
      if (om > mg || (om == mg && oi < ig)) { mg = om; ig = oi; }
    }
    float part = sA * expf(mA - mg) + (a2 ? sB * expf(mB - mg) : 0.f);
    float S = wsum64(part);
    if (lane == 0) { wsf[WS_MS + b * 2] = mg; wsf[WS_MS + b * 2 + 1] = S; }
    if (t <= 63) {  // build row t-1
      float y = emb[ig * 64 + lane] + wsf[WS_PE + (t - 1) * 64 + lane];
      float qn = proj_lds(y, myxb, sa_W, sa_b, lane);
      float kn = proj_lds(y, myxb, sa_W + 4096, sa_b + 64, lane);
      float vn = proj_lds(y, myxb, sa_W + 2 * 4096, sa_b + 128, lane);
      wsf[WS_X1 + b * 4096 + (t - 1) * 64 + lane] = y;
      wsf[WS_Q1 + b * 4096 + (t - 1) * 64 + lane] = qn;
      wsf[WS_K1 + b * 4096 + (t - 1) * 64 + lane] = kn;
      wsf[WS_V1 + b * 4096 + (t - 1) * 64 + lane] = vn;
    }
  }
  __syncthreads();
  if (t > 63) return;  // t=64: reduce-only launch

  // ---- Phase B: stage K1/V1 into LDS; load owned rows' x,q ----
  for (int r = wvid; r < t; r += 16) {
    K1[r * 65 + lane] = wsf[WS_K1 + b * 4096 + r * 64 + lane];
    V1[r * 65 + lane] = wsf[WS_V1 + b * 4096 + r * 64 + lane];
  }
  float xr[4], qr[4];
#pragma unroll
  for (int j = 0; j < 4; ++j) {
    int row = wvid + 16 * j;
    xr[j] = (row < t) ? wsf[WS_X1 + b * 4096 + row * 64 + lane] : 0.f;
    qr[j] = (row < t) ? wsf[WS_Q1 + b * 4096 + row * 64 + lane] : 0.f;
  }
  __syncthreads();

  // ---- Phase C: layer-1, one row per wave slot ----
#pragma unroll
  for (int j = 0; j < 4; ++j) {
    int row = wvid + 16 * j;
    if (row < t) {
      float out = transformer_row(lane, t, xr[j], qr[j], K1, V1, wvl, myxb, mypb, L0);
      float k2 = proj_lds(out, myxb, sa_W + 5 * 4096, sa_b + 5 * 64, lane);
      float v2 = proj_lds(out, myxb, sa_W + 6 * 4096, sa_b + 6 * 64, lane);
      K2[row * 65 + lane] = k2;
      V2[row * 65 + lane] = v2;
      if (row == t - 1) x2s[lane] = out;
    }
  }
  __syncthreads();

  // ---- Phase D: layer-2 row t-1 (wave 0) -> tokf ----
  if (wvid == 0) {
    float x2 = x2s[lane];
    float q2 = proj_lds(x2, myxb, sa_W + 4 * 4096, sa_b + 4 * 64, lane);
    float tf = transformer_row(lane, t, x2, q2, K2, V2, wvl, myxb, mypb, L1);
    wsf[WS_TOKF + b * 64 + lane] = tf;
  }
}

// =================== vocab step t: 99 blocks x 512 ===================
// t>=2: finalize dout row t-2 in place (raw logits -> probs) using mS(t-1).
// t<=63: compute logits(t) from tokf, store raw into dout row t-1 + per-block stats.
__global__ __launch_bounds__(512) void vocab_kernel(
    const float* __restrict__ soft_W, const float* __restrict__ soft_b,
    float* __restrict__ wsf, float* __restrict__ dout, int t) {
  const int tid = threadIdx.x, lane = tid & 63, wvid = tid >> 6;  // 8 waves
  const int jb = blockIdx.x;
  const int v = jb * VCOLS + tid;
  const bool valid = v < Vc;
  __shared__ float f2[512];
  __shared__ float sm[64];  __shared__ int si[64];
  __shared__ float ssm[64];
  __shared__ float bmx[8];  __shared__ int bix[8];

  // ---- Phase A: finalize dout row t-2 ----
  if (t >= 2 && valid) {
    long row = (long)(t - 2) * Vc + v;
#pragma unroll
    for (int b2 = 0; b2 < 8; ++b2) {
      float m = wsf[WS_MS + b2 * 2], S = wsf[WS_MS + b2 * 2 + 1];
      long idx = (long)b2 * 63 * Vc + row;
      dout[idx] = expf(dout[idx] - m) / S;
    }
  }
  if (t > 63) return;

  // ---- Phase B: logits(t) ----
  f2[tid] = wsf[WS_TOKF + (tid & 7) * 64 + (tid >> 3)];  // f2[e*8+b]
  __syncthreads();
  float sb = valid ? soft_b[v] : 0.f;
  float lg[8];
#pragma unroll
  for (int b = 0; b < 8; ++b) lg[b] = valid ? sb : NEG_INF;
  if (valid) {
    const float4* f4 = (const float4*)f2;
    const float* col = soft_W + v;
#pragma unroll 8
    for (int e = 0; e < 64; ++e) {
      float wc = col[(long)e * Vc];
      float4 fa = f4[2 * e], fb = f4[2 * e + 1];
      lg[0] = fmaf(fa.x, wc, lg[0]);
      lg[1] = fmaf(fa.y, wc, lg[1]);
      lg[2] = fmaf(fa.z, wc, lg[2]);
      lg[3] = fmaf(fa.w, wc, lg[3]);
      lg[4] = fmaf(fb.x, wc, lg[4]);
      lg[5] = fmaf(fb.y, wc, lg[5]);
      lg[6] = fmaf(fb.z, wc, lg[6]);
      lg[7] = fmaf(fb.w, wc, lg[7]);
    }
  }
#pragma unroll
  for (int b = 0; b < 8; ++b) {
    float m = lg[b]; int ix = valid ? v : 0x7fffffff;
#pragma unroll
    for (int msk = 1; msk < 64; msk <<= 1) {
      float om = __shfl_xor(m, msk, 64);
      int oi = __shfl_xor(ix, msk, 64);
      if (om > m || (om == m && oi < ix)) { m = om; ix = oi; }
    }
    if (lane == 0) { sm[wvid * 8 + b] = m; si[wvid * 8 + b] = ix; }
  }
  __syncthreads();
  if (tid < 8) {
    float m = NEG_INF; int ix = 0x7fffffff;
    for (int wv = 0; wv < 8; ++wv) {
      float om = sm[wv * 8 + tid]; int oi = si[wv * 8 + tid];
      if (om > m || (om == m && oi < ix)) { m = om; ix = oi; }
    }
    bmx[tid] = m; bix[tid] = ix;
  }
  __syncthreads();
#pragma unroll
  for (int b = 0; b < 8; ++b) {
    float c = valid ? expf(lg[b] - bmx[b]) : 0.f;
    float s = wsum64(c);
    if (lane == 0) ssm[wvid * 8 + b] = s;
  }
  __syncthreads();
  if (tid < 8) {
    float s = 0.f;
    for (int wv = 0; wv < 8; ++wv) s += ssm[wv * 8 + tid];
    wsf[WS_SM + tid * 128 + jb] = bmx[tid];
    wsf[WS_SS + tid * 128 + jb] = s;
    ((int*)(wsf + WS_SI))[tid * 128 + jb] = bix[tid];
  }
  // raw logits -> dout row t-1 (scratch; finalized next step)
  if (valid) {
    long row = (long)(t - 1) * Vc + v;
#pragma unroll
    for (int b = 0; b < 8; ++b) dout[(long)b * 63 * Vc + row] = lg[b];
  }
}

extern "C" void kernel_launch(void* const* d_in, const int* in_sizes, int n_in,
                              void* d_out, int out_size, void* d_ws, size_t ws_size,
                              hipStream_t stream) {
  (void)in_sizes; (void)n_in; (void)out_size; (void)ws_size;
  const float* noise  = (const float*)d_in[0];
  const float* lin_W  = (const float*)d_in[1];
  const float* lin_b  = (const float*)d_in[2];
  const float* sa_W   = (const float*)d_in[3];
  const float* sa_b   = (const float*)d_in[4];
  const float* ca_W   = (const float*)d_in[5];
  const float* ca_b   = (const float*)d_in[6];
  const float* ff_W1  = (const float*)d_in[7];
  const float* ff_b1  = (const float*)d_in[8];
  const float* ff_W2  = (const float*)d_in[9];
  const float* ff_b2  = (const float*)d_in[10];
  const float* ln_g   = (const float*)d_in[11];
  const float* ln_b   = (const float*)d_in[12];
  const float* emb    = (const float*)d_in[13];
  const float* soft_W = (const float*)d_in[14];
  const float* soft_b = (const float*)d_in[15];
  const int*   start  = (const int*)d_in[16];
  float* dout = (float*)d_out;
  float* wsf  = (float*)d_ws;

  init_kernel<<<1, 1024, 0, stream>>>(noise, lin_W, lin_b, sa_W, sa_b, ca_W,
                                      emb, start, wsf);
  for (int t = 1; t <= 64; ++t) {
    trans_kernel<<<NB, 1024, 0, stream>>>(sa_W, sa_b, ca_W, ca_b, ff_W1, ff_b1,
                                          ff_W2, ff_b2, ln_g, ln_b, emb, wsf, t);
    vocab_kernel<<<NVB, 512, 0, stream>>>(soft_W, soft_b, wsf, dout, t);
  }
}

// Round 8
// 3985.888 us; speedup vs baseline: 8.8212x; 8.8212x over previous
//
#include <hip/hip_runtime.h>
#include <math.h>

#define Vc 50257
#define NEG_INF (-__builtin_inff())
#define VCOLS 512
#define NVB 99      // 99*512 = 50688 >= 50257
#define NB  8

// ---- workspace float offsets (no flags/atomics; coherence = kernel boundaries) ----
#define WS_PE    0        // [64][64] pe rows (1..62 used)
#define WS_WV    4096     // [8][64]
#define WS_CS    4608     // [2 layers][2][64] column sums of ca_W k/v proj
#define WS_TOKF  4864     // [8][64]
#define WS_MS    5376     // [8][2]
#define WS_X2    5632     // [8][64] layer-1 out of row t-1
#define WS_SM    8192     // stats_m [8][128]
#define WS_SS    9216     // stats_s [8][128]
#define WS_SI    10240    // stats_i [8][128] (int)
#define WS_X1    16384    // [8][64][64]
#define WS_Q1    49152
#define WS_K1    81920
#define WS_V1    114688
#define WS_K2G   147456   // [8][64][64] layer-1 K2 outputs
#define WS_V2G   180224   // end 212992 floats (~852 KB)

// ---------------- wave-level helpers ----------------

__device__ __forceinline__ float wsum64(float v) {
#pragma unroll
  for (int m = 32; m >= 1; m >>= 1) v += __shfl_xor(v, m, 64);
  return v;
}

__device__ __forceinline__ float red8(float v) {
  v += __shfl_xor(v, 1, 64);
  v += __shfl_xor(v, 2, 64);
  v += __shfl_xor(v, 4, 64);
  return v;
}

// out[lane] = bias[lane] + sum_e x[e]*W[e*64+lane]; x broadcast via LDS float4 reads.
// W may live in LDS (staged) or global.
__device__ __forceinline__ float proj_lds(float xv, float* xb,
                                          const float* W,
                                          const float* __restrict__ bias, int lane) {
  xb[lane] = xv;
  asm volatile("s_waitcnt lgkmcnt(0)" ::: "memory");
  float acc = bias[lane];
  const float4* x4 = (const float4*)xb;
#pragma unroll
  for (int i = 0; i < 16; ++i) {
    float4 xc = x4[i];
    acc = fmaf(xc.x, W[(4 * i + 0) * 64 + lane], acc);
    acc = fmaf(xc.y, W[(4 * i + 1) * 64 + lane], acc);
    acc = fmaf(xc.z, W[(4 * i + 2) * 64 + lane], acc);
    acc = fmaf(xc.w, W[(4 * i + 3) * 64 + lane], acc);
  }
  asm volatile("" ::: "memory");
  return acc;
}

__device__ __forceinline__ float ln64(float xv, const float* __restrict__ g,
                                      const float* __restrict__ b, int lane) {
  float mean = wsum64(xv) * 0.015625f;
  float d = xv - mean;
  float var = wsum64(d * d) * 0.015625f;
  float r = 1.0f / sqrtf(var + 1e-5f);
  return d * r * g[lane] + b[lane];
}

struct LayerR {
  const float *saW3, *sab3, *caW0, *cab0, *caW3, *cab3,
              *ffW1, *ffb1, *ffW2, *ffb2, *g0, *be0, *g1, *be1, *g2, *be2;
  float cs1_r, cs2_r, cab1_r, cab2_r;
};

// saW3/caW0/caW3 point at LDS-staged copies; ff at global.
__device__ __forceinline__ void build_layer_s(LayerR& L, int n, int lane,
    const float* sWl, const float* sa_b, const float* ca_b,
    const float* ff_W1, const float* ff_b1, const float* ff_W2, const float* ff_b2,
    const float* ln_g, const float* ln_b, const float* cs_g) {
  L.saW3 = sWl;              L.sab3 = sa_b + (n * 4 + 3) * 64;
  L.caW0 = sWl + 4096;       L.cab0 = ca_b + (n * 4 + 0) * 64;
  L.caW3 = sWl + 2 * 4096;   L.cab3 = ca_b + (n * 4 + 3) * 64;
  L.ffW1 = ff_W1 + n * 4096; L.ffb1 = ff_b1 + n * 64;
  L.ffW2 = ff_W2 + n * 4096; L.ffb2 = ff_b2 + n * 64;
  L.g0 = ln_g + (n * 3 + 0) * 64;  L.be0 = ln_b + (n * 3 + 0) * 64;
  L.g1 = ln_g + (n * 3 + 1) * 64;  L.be1 = ln_b + (n * 3 + 1) * 64;
  L.g2 = ln_g + (n * 3 + 2) * 64;  L.be2 = ln_b + (n * 3 + 2) * 64;
  L.cab1_r = ca_b[(n * 4 + 1) * 64 + lane];
  L.cab2_r = ca_b[(n * 4 + 2) * 64 + lane];
  L.cs1_r = cs_g[(n * 2 + 0) * 64 + lane];
  L.cs2_r = cs_g[(n * 2 + 1) * 64 + lane];
}

// One wave, one row. K/V in LDS with row stride 65.
__device__ float transformer_row(int lane, int t, float x, float q,
                                 const float* Kb, const float* Vb,
                                 const float* wv, float* xb, float* pb,
                                 const LayerR& P) {
  const float ISQ8 = 0.35355339059327373f;  // 1/sqrt(8)
  // ---- scores: lane = k ----
  xb[lane] = q;
  asm volatile("s_waitcnt lgkmcnt(0)" ::: "memory");
  float a[8] = {0.f, 0.f, 0.f, 0.f, 0.f, 0.f, 0.f, 0.f};
  const float* Krow = Kb + lane * 65;
  const float4* xq4 = (const float4*)xb;
#pragma unroll
  for (int i = 0; i < 16; ++i) {
    float4 xc = xq4[i];
    a[i >> 1] = fmaf(xc.x, Krow[4 * i + 0], a[i >> 1]);
    a[i >> 1] = fmaf(xc.y, Krow[4 * i + 1], a[i >> 1]);
    a[i >> 1] = fmaf(xc.z, Krow[4 * i + 2], a[i >> 1]);
    a[i >> 1] = fmaf(xc.w, Krow[4 * i + 3], a[i >> 1]);
  }
  const bool act = lane < t;
  float m[8];
#pragma unroll
  for (int h = 0; h < 8; ++h) { a[h] = act ? a[h] * ISQ8 : NEG_INF; m[h] = a[h]; }
#pragma unroll
  for (int msk = 1; msk < 64; msk <<= 1) {
#pragma unroll
    for (int h = 0; h < 8; ++h) m[h] = fmaxf(m[h], __shfl_xor(m[h], msk, 64));
  }
  float l[8];
#pragma unroll
  for (int h = 0; h < 8; ++h) { a[h] = act ? expf(a[h] - m[h]) : 0.f; l[h] = a[h]; }
#pragma unroll
  for (int msk = 1; msk < 64; msk <<= 1) {
#pragma unroll
    for (int h = 0; h < 8; ++h) l[h] += __shfl_xor(l[h], msk, 64);
  }
#pragma unroll
  for (int h = 0; h < 8; ++h) pb[h * 64 + lane] = a[h] / l[h];
  asm volatile("s_waitcnt lgkmcnt(0)" ::: "memory");
  // ---- PV: lane = e ----
  const float* pr = pb + (lane >> 3) * 64;
  float attn = 0.f;
  for (int k = 0; k < t; ++k) attn = fmaf(pr[k], Vb[k * 65 + lane], attn);

  float y1 = ln64(x + proj_lds(attn, xb, P.saW3, P.sab3, lane), P.g0, P.be0, lane);
  float qc = proj_lds(y1, xb, P.caW0, P.cab0, lane);
  float pa = red8(qc * P.cs1_r);
  float pc = red8(qc * P.cab1_r);
  const float4* wv4 = (const float4*)wv;
  float mc = NEG_INF;
#pragma unroll
  for (int i = 0; i < 16; ++i) {
    float4 wq = wv4[i];
    int k = 4 * i;
    if (k + 0 < t) mc = fmaxf(mc, fmaf(pa, wq.x, pc));
    if (k + 1 < t) mc = fmaxf(mc, fmaf(pa, wq.y, pc));
    if (k + 2 < t) mc = fmaxf(mc, fmaf(pa, wq.z, pc));
    if (k + 3 < t) mc = fmaxf(mc, fmaf(pa, wq.w, pc));
  }
  float lc = 0.f, z = 0.f;
#pragma unroll
  for (int i = 0; i < 16; ++i) {
    float4 wq = wv4[i];
    int k = 4 * i;
    float wk[4] = {wq.x, wq.y, wq.z, wq.w};
#pragma unroll
    for (int j = 0; j < 4; ++j) {
      if (k + j < t) {
        float raw = fmaf(pa, wk[j], pc);
        float pw = expf((raw - mc) * ISQ8);
        lc += pw;
        z = fmaf(pw, wk[j], z);
      }
    }
  }
  float oc = fmaf(z / lc, P.cs2_r, P.cab2_r);
  float y2 = ln64(y1 + proj_lds(oc, xb, P.caW3, P.cab3, lane), P.g1, P.be1, lane);
  float f = fmaxf(proj_lds(y2, xb, P.ffW1, P.ffb1, lane), 0.f);
  float y3 = ln64(y2 + proj_lds(f, xb, P.ffW2, P.ffb2, lane), P.g2, P.be2, lane);
  return y3;
}

// =================== init: pe table, w-vector, ca column sums, seed row 0 ===================
__global__ __launch_bounds__(1024) void init_kernel(
    const float* __restrict__ noise, const float* __restrict__ lin_W,
    const float* __restrict__ lin_b, const float* __restrict__ sa_W,
    const float* __restrict__ sa_b, const float* __restrict__ ca_W,
    const float* __restrict__ emb, const int* __restrict__ start_id,
    float* __restrict__ wsf) {
  const int tid = threadIdx.x, lane = tid & 63, wvid = tid >> 6;
  __shared__ float xbuf[16 * 64];
  float* myxb = xbuf + wvid * 64;

  for (int i = tid; i < 62 * 64; i += 1024) {
    int t = 1 + (i >> 6), e = i & 63;
    double ang = (double)t / pow(10000.0, (double)(e & 62) / 64.0);
    wsf[WS_PE + t * 64 + e] = (e & 1) ? (float)cos(ang) : (float)sin(ang);
  }
  if (wvid < 8) {
    int b = wvid;
    float nz = noise[b * 64 + lane];
    float t1 = proj_lds(nz, myxb, lin_W, lin_b, lane);
    wsf[WS_WV + b * 64 + lane] = proj_lds(t1, myxb, lin_W + 4096, lin_b + 64, lane);
  } else if (wvid < 12) {
    int w = wvid - 8, n = w >> 1, which = w & 1;
    float c = 0.f;
    for (int e = 0; e < 64; ++e) c += ca_W[(n * 4 + 1 + which) * 4096 + e * 64 + lane];
    wsf[WS_CS + w * 64 + lane] = c;
  } else {
    for (int b = (wvid - 12) * 2; b <= (wvid - 12) * 2 + 1; ++b) {
      float y0 = emb[start_id[0] * 64 + lane] + ((lane & 1) ? 1.0f : 0.0f);
      float q0 = proj_lds(y0, myxb, sa_W, sa_b, lane);
      float k0 = proj_lds(y0, myxb, sa_W + 4096, sa_b + 64, lane);
      float v0 = proj_lds(y0, myxb, sa_W + 2 * 4096, sa_b + 128, lane);
      wsf[WS_X1 + b * 4096 + lane] = y0;
      wsf[WS_Q1 + b * 4096 + lane] = q0;
      wsf[WS_K1 + b * 4096 + lane] = k0;
      wsf[WS_V1 + b * 4096 + lane] = v0;
    }
  }
}

// =================== layer-1 step t: 32 blocks (4/batch), 1 row/wave ===================
// Each block: stage L0 weights->LDS, stage K1/V1, redundant A-phase
// (reduce stats(t-1) -> mS,argmax; build row t-1), then layer-1 rows.
__global__ __launch_bounds__(1024) void l1_kernel(
    const float* __restrict__ sa_W, const float* __restrict__ sa_b,
    const float* __restrict__ ca_W, const float* __restrict__ ca_b,
    const float* __restrict__ ff_W1, const float* __restrict__ ff_b1,
    const float* __restrict__ ff_W2, const float* __restrict__ ff_b2,
    const float* __restrict__ ln_g, const float* __restrict__ ln_b,
    const float* __restrict__ emb, float* __restrict__ wsf, int t) {
  const int tid = threadIdx.x, lane = tid & 63, wvid = tid >> 6;
  const int b = blockIdx.x >> 2, sb = blockIdx.x & 3;
  __shared__ float lds[29888];          // 119552 B
  float* sW   = lds;                    // 3 x 4096 (saW3, caW0, caW3)
  float* K1l  = lds + 12288;            // 63 rows stride 65
  float* V1l  = lds + 16384;
  float* wvl  = lds + 20480;
  float* ynew = lds + 20544;
  float* qnew = lds + 20608;
  float* xbuf = lds + 20672;            // 16 x 64
  float* pbuf = lds + 21696;            // 16 x 512
  float* myxb = xbuf + wvid * 64;
  float* mypb = pbuf + wvid * 512;

  if (t <= 63) {
    // ---- stage weights (3 x 1024 float4, one per thread) ----
    float4* d = (float4*)sW;
    d[tid]        = ((const float4*)(sa_W + 3 * 4096))[tid];
    d[1024 + tid] = ((const float4*)(ca_W))[tid];
    d[2048 + tid] = ((const float4*)(ca_W + 3 * 4096))[tid];
    // ---- stage K1/V1 rows 0..t-2 (t>=2) or row 0 (t==1) ----
    int upto = (t >= 2) ? t - 1 : t;
    for (int r = wvid; r < upto; r += 16) {
      K1l[r * 65 + lane] = wsf[WS_K1 + b * 4096 + r * 64 + lane];
      V1l[r * 65 + lane] = wsf[WS_V1 + b * 4096 + r * 64 + lane];
    }
    if (wvid == 1) wvl[lane] = wsf[WS_WV + b * 64 + lane];
  }

  // ---- A-phase (wave 0): reduce vocab stats(t-1); build row t-1 ----
  if (t >= 2 && wvid == 0) {
    const float* smp = wsf + WS_SM + b * 128;
    const float* ssp = wsf + WS_SS + b * 128;
    const int*   sip = (const int*)(wsf + WS_SI) + b * 128;
    float mA = smp[lane];
    float sA = ssp[lane];
    int   iA = sip[lane];
    const bool a2 = (64 + lane) < NVB;
    float mB = a2 ? smp[64 + lane] : NEG_INF;
    float sB = a2 ? ssp[64 + lane] : 0.f;
    int   iB = a2 ? sip[64 + lane] : 0x7fffffff;
    float mg = mA; int ig = iA;
    if (mB > mg || (mB == mg && iB < ig)) { mg = mB; ig = iB; }
#pragma unroll
    for (int msk = 1; msk < 64; msk <<= 1) {
      float om = __shfl_xor(mg, msk, 64);
      int oi = __shfl_xor(ig, msk, 64);
      if (om > mg || (om == mg && oi < ig)) { mg = om; ig = oi; }
    }
    float part = sA * expf(mA - mg) + (a2 ? sB * expf(mB - mg) : 0.f);
    float S = wsum64(part);
    if (lane == 0) { wsf[WS_MS + b * 2] = mg; wsf[WS_MS + b * 2 + 1] = S; }
    if (t <= 63) {
      float y = emb[ig * 64 + lane] + wsf[WS_PE + (t - 1) * 64 + lane];
      float qn = proj_lds(y, myxb, sa_W, sa_b, lane);
      float kn = proj_lds(y, myxb, sa_W + 4096, sa_b + 64, lane);
      float vn = proj_lds(y, myxb, sa_W + 2 * 4096, sa_b + 128, lane);
      K1l[(t - 1) * 65 + lane] = kn;
      V1l[(t - 1) * 65 + lane] = vn;
      ynew[lane] = y; qnew[lane] = qn;
      if (sb == ((t - 1) >> 4)) {  // owner block persists row t-1 to ws
        wsf[WS_X1 + b * 4096 + (t - 1) * 64 + lane] = y;
        wsf[WS_Q1 + b * 4096 + (t - 1) * 64 + lane] = qn;
        wsf[WS_K1 + b * 4096 + (t - 1) * 64 + lane] = kn;
        wsf[WS_V1 + b * 4096 + (t - 1) * 64 + lane] = vn;
      }
    }
  }
  __syncthreads();
  if (t > 63) return;  // t=64: reduce-only launch

  // ---- layer-1: one row per wave ----
  const int row = sb * 16 + wvid;
  if (row < t) {
    float x_r, q_r;
    if (t >= 2 && row == t - 1) { x_r = ynew[lane]; q_r = qnew[lane]; }
    else {
      x_r = wsf[WS_X1 + b * 4096 + row * 64 + lane];
      q_r = wsf[WS_Q1 + b * 4096 + row * 64 + lane];
    }
    LayerR L0;
    build_layer_s(L0, 0, lane, sW, sa_b, ca_b, ff_W1, ff_b1, ff_W2, ff_b2,
                  ln_g, ln_b, wsf + WS_CS);
    float out = transformer_row(lane, t, x_r, q_r, K1l, V1l, wvl, myxb, mypb, L0);
    float k2 = proj_lds(out, myxb, sa_W + 5 * 4096, sa_b + 5 * 64, lane);
    float v2 = proj_lds(out, myxb, sa_W + 6 * 4096, sa_b + 6 * 64, lane);
    wsf[WS_K2G + b * 4096 + row * 64 + lane] = k2;
    wsf[WS_V2G + b * 4096 + row * 64 + lane] = v2;
    if (row == t - 1) wsf[WS_X2 + b * 64 + lane] = out;
  }
}

// =================== layer-2 step t: 8 blocks ===================
__global__ __launch_bounds__(1024) void l2_kernel(
    const float* __restrict__ sa_W, const float* __restrict__ sa_b,
    const float* __restrict__ ca_W, const float* __restrict__ ca_b,
    const float* __restrict__ ff_W1, const float* __restrict__ ff_b1,
    const float* __restrict__ ff_W2, const float* __restrict__ ff_b2,
    const float* __restrict__ ln_g, const float* __restrict__ ln_b,
    float* __restrict__ wsf, int t) {
  const int tid = threadIdx.x, lane = tid & 63, wvid = tid >> 6;
  const int b = blockIdx.x;
  __shared__ float lds[22592];          // 90368 B
  float* sW   = lds;                    // 3 x 4096 (saW3 n1, caW0 n1, caW3 n1)
  float* K2l  = lds + 12288;
  float* V2l  = lds + 16384;
  float* wvl  = lds + 20480;
  float* xbuf = lds + 20544;            // wave0 only needs 64; keep 16x64
  float* pbuf = lds + 21568;            // 512 (wave 0)
  float* myxb = xbuf + wvid * 64;

  float4* d = (float4*)sW;
  d[tid]        = ((const float4*)(sa_W + 7 * 4096))[tid];
  d[1024 + tid] = ((const float4*)(ca_W + 4 * 4096))[tid];
  d[2048 + tid] = ((const float4*)(ca_W + 7 * 4096))[tid];
  for (int r = wvid; r < t; r += 16) {
    K2l[r * 65 + lane] = wsf[WS_K2G + b * 4096 + r * 64 + lane];
    V2l[r * 65 + lane] = wsf[WS_V2G + b * 4096 + r * 64 + lane];
  }
  if (wvid == 1) wvl[lane] = wsf[WS_WV + b * 64 + lane];
  __syncthreads();

  if (wvid == 0) {
    LayerR L1;
    build_layer_s(L1, 1, lane, sW, sa_b, ca_b, ff_W1, ff_b1, ff_W2, ff_b2,
                  ln_g, ln_b, wsf + WS_CS);
    float x2 = wsf[WS_X2 + b * 64 + lane];
    float q2 = proj_lds(x2, myxb, sa_W + 4 * 4096, sa_b + 4 * 64, lane);
    float tf = transformer_row(lane, t, x2, q2, K2l, V2l, wvl, myxb, pbuf, L1);
    wsf[WS_TOKF + b * 64 + lane] = tf;
  }
}

// =================== vocab step t: 99 blocks x 512 ===================
// t>=2: finalize dout row t-2 (raw logits -> probs) using mS.
// t<=63: logits(t) -> dout row t-1 (raw) + per-block stats.
__global__ __launch_bounds__(512) void vocab_kernel(
    const float* __restrict__ soft_W, const float* __restrict__ soft_b,
    float* __restrict__ wsf, float* __restrict__ dout, int t) {
  const int tid = threadIdx.x, lane = tid & 63, wvid = tid >> 6;  // 8 waves
  const int jb = blockIdx.x;
  const int v = jb * VCOLS + tid;
  const bool valid = v < Vc;
  __shared__ float f2[512];
  __shared__ float sm[64];  __shared__ int si[64];
  __shared__ float ssm[64];
  __shared__ float bmx[8];  __shared__ int bix[8];

  if (t >= 2 && valid) {
    long row = (long)(t - 2) * Vc + v;
#pragma unroll
    for (int b2 = 0; b2 < 8; ++b2) {
      float m = wsf[WS_MS + b2 * 2], S = wsf[WS_MS + b2 * 2 + 1];
      long idx = (long)b2 * 63 * Vc + row;
      dout[idx] = expf(dout[idx] - m) / S;
    }
  }
  if (t > 63) return;

  f2[tid] = wsf[WS_TOKF + (tid & 7) * 64 + (tid >> 3)];  // f2[e*8+b]
  __syncthreads();
  float sb = valid ? soft_b[v] : 0.f;
  float lg[8];
#pragma unroll
  for (int b = 0; b < 8; ++b) lg[b] = valid ? sb : NEG_INF;
  if (valid) {
    const float4* f4 = (const float4*)f2;
    const float* col = soft_W + v;
#pragma unroll 8
    for (int e = 0; e < 64; ++e) {
      float wc = col[(long)e * Vc];
      float4 fa = f4[2 * e], fb = f4[2 * e + 1];
      lg[0] = fmaf(fa.x, wc, lg[0]);
      lg[1] = fmaf(fa.y, wc, lg[1]);
      lg[2] = fmaf(fa.z, wc, lg[2]);
      lg[3] = fmaf(fa.w, wc, lg[3]);
      lg[4] = fmaf(fb.x, wc, lg[4]);
      lg[5] = fmaf(fb.y, wc, lg[5]);
      lg[6] = fmaf(fb.z, wc, lg[6]);
      lg[7] = fmaf(fb.w, wc, lg[7]);
    }
  }
#pragma unroll
  for (int b = 0; b < 8; ++b) {
    float m = lg[b]; int ix = valid ? v : 0x7fffffff;
#pragma unroll
    for (int msk = 1; msk < 64; msk <<= 1) {
      float om = __shfl_xor(m, msk, 64);
      int oi = __shfl_xor(ix, msk, 64);
      if (om > m || (om == m && oi < ix)) { m = om; ix = oi; }
    }
    if (lane == 0) { sm[wvid * 8 + b] = m; si[wvid * 8 + b] = ix; }
  }
  __syncthreads();
  if (tid < 8) {
    float m = NEG_INF; int ix = 0x7fffffff;
    for (int wv = 0; wv < 8; ++wv) {
      float om = sm[wv * 8 + tid]; int oi = si[wv * 8 + tid];
      if (om > m || (om == m && oi < ix)) { m = om; ix = oi; }
    }
    bmx[tid] = m; bix[tid] = ix;
  }
  __syncthreads();
#pragma unroll
  for (int b = 0; b < 8; ++b) {
    float c = valid ? expf(lg[b] - bmx[b]) : 0.f;
    float s = wsum64(c);
    if (lane == 0) ssm[wvid * 8 + b] = s;
  }
  __syncthreads();
  if (tid < 8) {
    float s = 0.f;
    for (int wv = 0; wv < 8; ++wv) s += ssm[wv * 8 + tid];
    wsf[WS_SM + tid * 128 + jb] = bmx[tid];
    wsf[WS_SS + tid * 128 + jb] = s;
    ((int*)(wsf + WS_SI))[tid * 128 + jb] = bix[tid];
  }
  if (valid) {
    long row = (long)(t - 1) * Vc + v;
#pragma unroll
    for (int b = 0; b < 8; ++b) dout[(long)b * 63 * Vc + row] = lg[b];
  }
}

extern "C" void kernel_launch(void* const* d_in, const int* in_sizes, int n_in,
                              void* d_out, int out_size, void* d_ws, size_t ws_size,
                              hipStream_t stream) {
  (void)in_sizes; (void)n_in; (void)out_size; (void)ws_size;
  const float* noise  = (const float*)d_in[0];
  const float* lin_W  = (const float*)d_in[1];
  const float* lin_b  = (const float*)d_in[2];
  const float* sa_W   = (const float*)d_in[3];
  const float* sa_b   = (const float*)d_in[4];
  const float* ca_W   = (const float*)d_in[5];
  const float* ca_b   = (const float*)d_in[6];
  const float* ff_W1  = (const float*)d_in[7];
  const float* ff_b1  = (const float*)d_in[8];
  const float* ff_W2  = (const float*)d_in[9];
  const float* ff_b2  = (const float*)d_in[10];
  const float* ln_g   = (const float*)d_in[11];
  const float* ln_b   = (const float*)d_in[12];
  const float* emb    = (const float*)d_in[13];
  const float* soft_W = (const float*)d_in[14];
  const float* soft_b = (const float*)d_in[15];
  const int*   start  = (const int*)d_in[16];
  float* dout = (float*)d_out;
  float* wsf  = (float*)d_ws;

  init_kernel<<<1, 1024, 0, stream>>>(noise, lin_W, lin_b, sa_W, sa_b, ca_W,
                                      emb, start, wsf);
  for (int t = 1; t <= 63; ++t) {
    l1_kernel<<<32, 1024, 0, stream>>>(sa_W, sa_b, ca_W, ca_b, ff_W1, ff_b1,
                                       ff_W2, ff_b2, ln_g, ln_b, emb, wsf, t);
    l2_kernel<<<NB, 1024, 0, stream>>>(sa_W, sa_b, ca_W, ca_b, ff_W1, ff_b1,
                                       ff_W2, ff_b2, ln_g, ln_b, wsf, t);
    vocab_kernel<<<NVB, 512, 0, stream>>>(soft_W, soft_b, wsf, dout, t);
  }
  l1_kernel<<<32, 1024, 0, stream>>>(sa_W, sa_b, ca_W, ca_b, ff_W1, ff_b1,
                                     ff_W2, ff_b2, ln_g, ln_b, emb, wsf, 64);
  vocab_kernel<<<NVB, 512, 0, stream>>>(soft_W, soft_b, wsf, dout, 64);
}